// Round 9
// baseline (402.075 us; speedup 1.0000x reference)
//
#include <hip/hip_runtime.h>
#include <hip/hip_bf16.h>

typedef __attribute__((ext_vector_type(8))) short bf16x8;
typedef __attribute__((ext_vector_type(4))) float f32x4;

__device__ __forceinline__ ushort f2bf(float f) {
  union { float f; unsigned u; } v; v.f = f;
  unsigned u = v.u;
  return (ushort)((u + 0x7FFFu + ((u >> 16) & 1u)) >> 16);
}
__device__ __forceinline__ float bf2f(ushort u) {
  union { unsigned u; float f; } v; v.u = ((unsigned)u) << 16;
  return v.f;
}
__device__ __forceinline__ float fsig(float x) {
  return __builtin_amdgcn_rcpf(1.0f + __expf(-x));
}
__device__ __forceinline__ float ftnh(float x) {
  float e = __expf(2.0f * x);
  return 1.0f - 2.0f * __builtin_amdgcn_rcpf(e + 1.0f);
}
__device__ __forceinline__ f32x4 MF(bf16x8 a, bf16x8 b, f32x4 c) {
  return __builtin_amdgcn_mfma_f32_16x16x32_bf16(a, b, c, 0, 0, 0);
}

// Repack layout (ushort units) in `wall`:
//  [0,131072)        whhrep [dir2][w8][lane64][frag16][8]
//  [131072,262144)   wihrep [dir2][wq4][j8][kk4][lane64][8]
//  [262144,294912)   linrep [w8][kk8][lane64][8]
//  [294912,425984)   emb_bf [1024][128]
__global__ __launch_bounds__(256) void repack_all2(
    const float* __restrict__ wihf, const float* __restrict__ whhf,
    const float* __restrict__ wihb, const float* __restrict__ whhb,
    const float* __restrict__ emb, const float* __restrict__ linw,
    ushort* __restrict__ wall) {
  int i = blockIdx.x * 256 + threadIdx.x;
  if (i < 131072) {
    int e = i & 7, f = (i >> 3) & 15, lane = (i >> 7) & 63, w = (i >> 13) & 7,
        d = (i >> 16) & 1;
    int nt = f >> 2, kk = f & 3;
    int pcol = w * 64 + nt * 16 + (lane & 15);
    int g = (pcol >> 4) & 3, h = (pcol >> 6) * 16 + (pcol & 15);
    int k = kk * 32 + (lane >> 4) * 8 + e;
    const float* src = d ? whhb : whhf;
    wall[i] = f2bf(src[(g * 128 + h) * 128 + k]);
  } else if (i < 262144) {
    int r = i - 131072;
    int e = r & 7, lane = (r >> 3) & 63, kk = (r >> 9) & 3, j = (r >> 11) & 7,
        wq = (r >> 14) & 3, d = (r >> 16) & 1;
    int pcol = wq * 128 + j * 16 + (lane & 15);
    int g = (pcol >> 4) & 3, h = (pcol >> 6) * 16 + (pcol & 15);
    int k = kk * 32 + (lane >> 4) * 8 + e;
    const float* src = d ? wihb : wihf;
    wall[i] = f2bf(src[(g * 128 + h) * 128 + k]);
  } else if (i < 294912) {
    int r = i - 262144;
    int e = r & 7, lane = (r >> 3) & 63, kk = (r >> 9) & 7, w = (r >> 12) & 7;
    int col = w * 16 + (lane & 15);
    int k = kk * 32 + (lane >> 4) * 8 + e;
    wall[i] = f2bf(linw[col * 256 + k]);
  } else if (i < 425984) {
    int r = i - 294912;
    wall[i] = f2bf(emb[r]);
  }
}

// Fused vocab pipeline: x-gates (-> gxv), leaf scan (T=2), leaf head+gates
// (-> gcv). One block per 16 vocab entries.
__global__ __launch_bounds__(512) void vocab_all(
    const ushort* __restrict__ emb_bf, const ushort* __restrict__ wihrep,
    const ushort* __restrict__ whhrep, const ushort* __restrict__ linrep,
    const float* __restrict__ linb, const float* __restrict__ bihf,
    const float* __restrict__ bhhf, const float* __restrict__ bihb,
    const float* __restrict__ bhhb, ushort* __restrict__ gxv,
    ushort* __restrict__ gcv) {
  __shared__ __align__(16) ushort sT[2048];
  __shared__ __align__(16) ushort sGx[16384];    // [16][1024] gates both dirs
  __shared__ __align__(16) ushort sHf[2][2048];  // leaf h, swizzled
  __shared__ __align__(16) ushort sH[2048];
  const int tid = threadIdx.x;
  const int w = tid >> 6, l = tid & 63, hlo = l & 15, lg = l >> 4;
  const int r0 = lg * 4, k0 = lg * 8;
  const int hcol = w * 16 + hlo;
  const int v0 = blockIdx.x * 16;

  // phase 1: x-gates of 16 vocab rows (w>>2 = dir)
  {
    int row = tid >> 5, col0 = (tid & 31) * 4;
    *(ushort4*)(sT + row * 128 + (col0 ^ ((row & 7) << 3))) =
        *(const ushort4*)(emb_bf + (size_t)(v0 + row) * 128 + col0);
  }
  __syncthreads();
  const int dd = w >> 2, wq = w & 3;
  {
    const ushort* wp = wihrep + (size_t)(dd * 4 + wq) * 16384 + l * 8;
    bf16x8 wfv[32];
#pragma unroll
    for (int j = 0; j < 8; ++j)
#pragma unroll
      for (int kk = 0; kk < 4; ++kk)
        wfv[j * 4 + kk] = *(const bf16x8*)(wp + j * 2048 + kk * 512);
    bf16x8 a[4];
#pragma unroll
    for (int kk = 0; kk < 4; ++kk)
      a[kk] = *(const bf16x8*)(sT + hlo * 128 + ((kk * 32 + k0) ^ ((hlo & 7) << 3)));
    f32x4 acc[8];
#pragma unroll
    for (int j = 0; j < 8; ++j) { f32x4 z = {0.f, 0.f, 0.f, 0.f}; acc[j] = z; }
#pragma unroll
    for (int kk = 0; kk < 4; ++kk)
#pragma unroll
      for (int j = 0; j < 8; ++j) acc[j] = MF(a[kk], wfv[j * 4 + kk], acc[j]);
#pragma unroll
    for (int p = 0; p < 2; ++p)
#pragma unroll
      for (int rg = 0; rg < 4; ++rg) {
        int hid = (wq * 2 + p) * 16 + hlo;
        ushort4 q = {f2bf(acc[p * 4 + 0][rg]), f2bf(acc[p * 4 + 1][rg]),
                     f2bf(acc[p * 4 + 2][rg]), f2bf(acc[p * 4 + 3][rg])};
        *(ushort4*)(gxv + (size_t)(v0 + r0 + rg) * 1024 + dd * 512 + hid * 4) = q;
        *(ushort4*)(sGx + (r0 + rg) * 1024 + dd * 512 + hid * 4) = q;
      }
  }
  __syncthreads();

  // phase 2: leaf scan T=2 per dir
  for (int d = 0; d < 2; ++d) {
    bf16x8 whh[16];
    {
      const ushort* p = whhrep + d * 65536 + w * 8192 + l * 128;
#pragma unroll
      for (int f = 0; f < 16; ++f) whh[f] = *(const bf16x8*)(p + f * 8);
    }
    const float* bih = d ? bihb : bihf;
    const float* bhh = d ? bhhb : bhhf;
    float bs[4];
#pragma unroll
    for (int nt = 0; nt < 4; ++nt)
      bs[nt] = bih[nt * 128 + hcol] + bhh[nt * 128 + hcol];
    ushort4 xg[4];
#pragma unroll
    for (int rg = 0; rg < 4; ++rg)
      xg[rg] = *(const ushort4*)(sGx + (r0 + rg) * 1024 + d * 512 + hcol * 4);
    float c_st[4], hn[4];
#pragma unroll
    for (int rg = 0; rg < 4; ++rg) {
      float g0 = bf2f(((const ushort*)&xg[rg])[0]) + bs[0];
      float g2 = bf2f(((const ushort*)&xg[rg])[2]) + bs[2];
      float g3 = bf2f(((const ushort*)&xg[rg])[3]) + bs[3];
      float c = fsig(g0) * ftnh(g2);
      c_st[rg] = c;
      hn[rg] = fsig(g3) * ftnh(c);
    }
#pragma unroll
    for (int rg = 0; rg < 4; ++rg) {
      int rr = r0 + rg;
      sH[rr * 128 + (hcol ^ ((rr & 7) << 3))] = f2bf(hn[rg]);
    }
    __syncthreads();
    f32x4 a4[4];
#pragma unroll
    for (int rg = 0; rg < 4; ++rg)
#pragma unroll
      for (int nt = 0; nt < 4; ++nt)
        a4[nt][rg] = bf2f(((const ushort*)&xg[rg])[nt]) + bs[nt];
    bf16x8 ah[4];
#pragma unroll
    for (int kk = 0; kk < 4; ++kk)
      ah[kk] = *(const bf16x8*)(sH + hlo * 128 + ((kk * 32 + k0) ^ ((hlo & 7) << 3)));
#pragma unroll
    for (int kk = 0; kk < 4; ++kk)
#pragma unroll
      for (int nt = 0; nt < 4; ++nt) a4[nt] = MF(ah[kk], whh[nt * 4 + kk], a4[nt]);
#pragma unroll
    for (int rg = 0; rg < 4; ++rg) {
      float iv = fsig(a4[0][rg]);
      float fv = fsig(a4[1][rg]);
      float gv = ftnh(a4[2][rg]);
      float ov = fsig(a4[3][rg]);
      float c = fv * c_st[rg] + iv * gv;
      int rr = r0 + rg;
      sHf[d][rr * 128 + (hcol ^ ((rr & 7) << 3))] = f2bf(ov * ftnh(c));
    }
    __syncthreads();
  }

  // phase 3: leaf head + gates -> gcv
  {
    const float lb = linb[hcol];
    f32x4 hac = {lb, lb, lb, lb};
#pragma unroll
    for (int kk = 0; kk < 8; ++kk) {
      bf16x8 lf = *(const bf16x8*)(linrep + w * 4096 + kk * 512 + l * 8);
      bf16x8 af = *(const bf16x8*)(&sHf[kk >> 2][0] + hlo * 128 +
                                   (((kk & 3) * 32 + k0) ^ ((hlo & 7) << 3)));
      hac = MF(af, lf, hac);
    }
#pragma unroll
    for (int rg = 0; rg < 4; ++rg) {
      int rr = r0 + rg;
      sT[rr * 128 + (hcol ^ ((rr & 7) << 3))] = f2bf(ftnh(hac[rg]));
    }
    __syncthreads();
    const ushort* wp = wihrep + (size_t)(dd * 4 + wq) * 16384 + l * 8;
    bf16x8 wfv[32];
#pragma unroll
    for (int j = 0; j < 8; ++j)
#pragma unroll
      for (int kk = 0; kk < 4; ++kk)
        wfv[j * 4 + kk] = *(const bf16x8*)(wp + j * 2048 + kk * 512);
    bf16x8 a[4];
#pragma unroll
    for (int kk = 0; kk < 4; ++kk)
      a[kk] = *(const bf16x8*)(sT + hlo * 128 + ((kk * 32 + k0) ^ ((hlo & 7) << 3)));
    f32x4 acc[8];
#pragma unroll
    for (int j = 0; j < 8; ++j) { f32x4 z = {0.f, 0.f, 0.f, 0.f}; acc[j] = z; }
#pragma unroll
    for (int kk = 0; kk < 4; ++kk)
#pragma unroll
      for (int j = 0; j < 8; ++j) acc[j] = MF(a[kk], wfv[j * 4 + kk], acc[j]);
#pragma unroll
    for (int p = 0; p < 2; ++p)
#pragma unroll
      for (int rg = 0; rg < 4; ++rg) {
        int hid = (wq * 2 + p) * 16 + hlo;
        ushort4 q = {f2bf(acc[p * 4 + 0][rg]), f2bf(acc[p * 4 + 1][rg]),
                     f2bf(acc[p * 4 + 2][rg]), f2bf(acc[p * 4 + 3][rg])};
        *(ushort4*)(gcv + (size_t)(v0 + r0 + rg) * 1024 + dd * 512 + hid * 4) = q;
      }
  }
}

// L7 scan: x-gates + child-gates gathered from vocab tables -> h7
__global__ __launch_bounds__(512) void scan7_k(
    const int* __restrict__ labels, const ushort* __restrict__ gxv,
    const ushort* __restrict__ gcv, const ushort* __restrict__ whhrep,
    const float* __restrict__ bihf, const float* __restrict__ bhhf,
    const float* __restrict__ bihb, const float* __restrict__ bhhb,
    ushort* __restrict__ h7) {
  __shared__ __align__(16) ushort sH[2][2048];
  const int tid = threadIdx.x;
  const int w = tid >> 6, l = tid & 63, hlo = l & 15, lg = l >> 4;
  const int r0 = lg * 4, k0 = lg * 8;
  const int hcol = w * 16 + hlo;
  const int d = blockIdx.y;
  const int g = blockIdx.x;

  bf16x8 whh[16];
  {
    const ushort* p = whhrep + d * 65536 + w * 8192 + l * 128;
#pragma unroll
    for (int f = 0; f < 16; ++f) whh[f] = *(const bf16x8*)(p + f * 8);
  }
  const float* bih = d ? bihb : bihf;
  const float* bhh = d ? bhhb : bhhf;
  float bs[4];
#pragma unroll
  for (int nt = 0; nt < 4; ++nt) bs[nt] = bih[nt * 128 + hcol] + bhh[nt * 128 + hcol];

  int nn[4];
  ushort4 xg[4];
#pragma unroll
  for (int rg = 0; rg < 4; ++rg) {
    nn[rg] = g * 16 + r0 + rg;
    int xr = labels[5461 + nn[rg]];
    xg[rg] = *(const ushort4*)(gxv + (size_t)xr * 1024 + d * 512 + hcol * 4);
  }
  ushort4 cg[2][4];
  {
    const int ci = d ? 3 : 0;
#pragma unroll
    for (int rg = 0; rg < 4; ++rg) {
      int cl = labels[21845 + nn[rg] * 4 + ci];
      cg[1][rg] = *(const ushort4*)(gcv + (size_t)cl * 1024 + d * 512 + hcol * 4);
    }
  }
  float c_st[4], hn[4];
#pragma unroll
  for (int t = 0; t < 6; ++t) {
    const bool isx = (t == 0) || (t == 5);
    f32x4 a4[4];
#pragma unroll
    for (int rg = 0; rg < 4; ++rg) {
      ushort4 u = isx ? xg[rg] : cg[t & 1][rg];
#pragma unroll
      for (int nt = 0; nt < 4; ++nt)
        a4[nt][rg] = bf2f(((const ushort*)&u)[nt]) + bs[nt];
    }
    if (t >= 1 && t <= 3) {
      const int ci = d ? (3 - t) : t;
#pragma unroll
      for (int rg = 0; rg < 4; ++rg) {
        int cl = labels[21845 + nn[rg] * 4 + ci];
        cg[(t + 1) & 1][rg] =
            *(const ushort4*)(gcv + (size_t)cl * 1024 + d * 512 + hcol * 4);
      }
    }
    if (t > 0) {
      bf16x8 ah[4];
#pragma unroll
      for (int kk = 0; kk < 4; ++kk)
        ah[kk] = *(const bf16x8*)(&sH[(t + 1) & 1][0] + hlo * 128 +
                                  ((kk * 32 + k0) ^ ((hlo & 7) << 3)));
#pragma unroll
      for (int kk = 0; kk < 4; ++kk)
#pragma unroll
        for (int nt = 0; nt < 4; ++nt) a4[nt] = MF(ah[kk], whh[nt * 4 + kk], a4[nt]);
    }
#pragma unroll
    for (int rg = 0; rg < 4; ++rg) {
      float iv = fsig(a4[0][rg]);
      float fv = fsig(a4[1][rg]);
      float gv = ftnh(a4[2][rg]);
      float ov = fsig(a4[3][rg]);
      float c = (t == 0) ? (iv * gv) : (fv * c_st[rg] + iv * gv);
      c_st[rg] = c;
      hn[rg] = ov * ftnh(c);
    }
    if (t < 5) {
#pragma unroll
      for (int rg = 0; rg < 4; ++rg) {
        int rr = r0 + rg;
        sH[t & 1][rr * 128 + (hcol ^ ((rr & 7) << 3))] = f2bf(hn[rg]);
      }
      __syncthreads();
    } else {
#pragma unroll
      for (int rg = 0; rg < 4; ++rg)
        h7[((size_t)d * 16384 + nn[rg]) * 128 + hcol] = f2bf(hn[rg]);
    }
  }
}

// "embedded finish + scan": finish child level's heads+gates -> sG, then
// 6-step scan of 16 nodes. hsrc/hdst may be LDS (swizzled) or global (linear).
__device__ __forceinline__ void scan_embed2(
    int g, int d, int cnt, const int* __restrict__ xlab,
    const ushort* __restrict__ gxv, const ushort* hsrc, int sstride, int ccnt,
    bool sswz, ushort* hdst, int dstride, bool dswz,
    const ushort* __restrict__ wihrep, const ushort* __restrict__ whhrep,
    const ushort* __restrict__ linrep, const float* __restrict__ linb,
    const float* __restrict__ bihf, const float* __restrict__ bhhf,
    const float* __restrict__ bihb, const float* __restrict__ bhhb,
    ushort* sG, ushort* sHb, ushort* sT) {
  const int tid = threadIdx.x;
  const int w = tid >> 6, l = tid & 63, hlo = l & 15, lg = l >> 4;
  const int r0 = lg * 4, k0 = lg * 8;
  const int hcol = w * 16 + hlo;

  // ---- finish child level: head + gates(dir d) -> sG ----
  bf16x8 wf[16];
  {
    const ushort* wp = wihrep + (size_t)(d * 4 + (w >> 1)) * 16384 +
                       (size_t)((w & 1) * 4) * 2048 + l * 8;
#pragma unroll
    for (int jj = 0; jj < 4; ++jj)
#pragma unroll
      for (int kk = 0; kk < 4; ++kk)
        wf[jj * 4 + kk] = *(const bf16x8*)(wp + jj * 2048 + kk * 512);
  }
  const float lb = linb[hcol];
  const int ntile = min(4, (ccnt - g * 64 + 15) >> 4);
  for (int tt = 0; tt < ntile; ++tt) {
    f32x4 hac = {lb, lb, lb, lb};
    int cr = g * 64 + tt * 16 + hlo;
    if (cr >= ccnt) cr = ccnt - 1;
    const int swk = sswz ? ((cr & 7) << 3) : 0;
#pragma unroll
    for (int kk = 0; kk < 8; ++kk) {
      bf16x8 lf = *(const bf16x8*)(linrep + w * 4096 + kk * 512 + l * 8);
      bf16x8 af = *(const bf16x8*)(hsrc + ((size_t)(kk >> 2) * sstride + cr) * 128 +
                                   (((kk & 3) * 32 + k0) ^ swk));
      hac = MF(af, lf, hac);
    }
    __syncthreads();
#pragma unroll
    for (int rg = 0; rg < 4; ++rg) {
      int rr = r0 + rg;
      sT[rr * 128 + (hcol ^ ((rr & 7) << 3))] = f2bf(ftnh(hac[rg]));
    }
    __syncthreads();
    bf16x8 a[4];
#pragma unroll
    for (int kk = 0; kk < 4; ++kk)
      a[kk] = *(const bf16x8*)(sT + hlo * 128 + ((kk * 32 + k0) ^ ((hlo & 7) << 3)));
    f32x4 acc[4];
#pragma unroll
    for (int jj = 0; jj < 4; ++jj) { f32x4 z = {0.f, 0.f, 0.f, 0.f}; acc[jj] = z; }
#pragma unroll
    for (int kk = 0; kk < 4; ++kk)
#pragma unroll
      for (int jj = 0; jj < 4; ++jj) acc[jj] = MF(a[kk], wf[jj * 4 + kk], acc[jj]);
    const int hid = (w >> 1) * 32 + (w & 1) * 16 + hlo;
#pragma unroll
    for (int rg = 0; rg < 4; ++rg) {
      int lrow = tt * 16 + r0 + rg;
      int sw = ((((lrow >> 4) & 3) ^ ((lrow >> 2) & 3)) << 4);
      ushort4 q = {f2bf(acc[0][rg]), f2bf(acc[1][rg]), f2bf(acc[2][rg]),
                   f2bf(acc[3][rg])};
      *(ushort4*)(sG + lrow * 512 + ((hid * 4) ^ sw)) = q;
    }
  }
  __syncthreads();

  // ---- scan ----
  bf16x8 whh[16];
  {
    const ushort* p = whhrep + d * 65536 + w * 8192 + l * 128;
#pragma unroll
    for (int f = 0; f < 16; ++f) whh[f] = *(const bf16x8*)(p + f * 8);
  }
  const float* bih = d ? bihb : bihf;
  const float* bhh = d ? bhhb : bhhf;
  float bs[4];
#pragma unroll
  for (int nt = 0; nt < 4; ++nt) bs[nt] = bih[nt * 128 + hcol] + bhh[nt * 128 + hcol];

  int nn[4];
  ushort4 xg[4];
#pragma unroll
  for (int rg = 0; rg < 4; ++rg) {
    nn[rg] = g * 16 + r0 + rg;
    int cl = nn[rg] < cnt ? nn[rg] : cnt - 1;
    xg[rg] = *(const ushort4*)(gxv + (size_t)xlab[cl] * 1024 + d * 512 + hcol * 4);
  }
  float c_st[4], hn[4];
#pragma unroll
  for (int t = 0; t < 6; ++t) {
    const bool isx = (t == 0) || (t == 5);
    f32x4 a4[4];
#pragma unroll
    for (int rg = 0; rg < 4; ++rg) {
      ushort4 u;
      if (isx) {
        u = xg[rg];
      } else {
        const int ci = d ? (4 - t) : (t - 1);
        int lrow = (r0 + rg) * 4 + ci;
        int sw = ((((lrow >> 4) & 3) ^ ((lrow >> 2) & 3)) << 4);
        u = *(const ushort4*)(sG + lrow * 512 + ((hcol * 4) ^ sw));
      }
#pragma unroll
      for (int nt = 0; nt < 4; ++nt)
        a4[nt][rg] = bf2f(((const ushort*)&u)[nt]) + bs[nt];
    }
    if (t > 0) {
      bf16x8 ah[4];
#pragma unroll
      for (int kk = 0; kk < 4; ++kk)
        ah[kk] = *(const bf16x8*)(sHb + ((t + 1) & 1) * 2048 + hlo * 128 +
                                  ((kk * 32 + k0) ^ ((hlo & 7) << 3)));
#pragma unroll
      for (int kk = 0; kk < 4; ++kk)
#pragma unroll
        for (int nt = 0; nt < 4; ++nt) a4[nt] = MF(ah[kk], whh[nt * 4 + kk], a4[nt]);
    }
#pragma unroll
    for (int rg = 0; rg < 4; ++rg) {
      float iv = fsig(a4[0][rg]);
      float fv = fsig(a4[1][rg]);
      float gv = ftnh(a4[2][rg]);
      float ov = fsig(a4[3][rg]);
      float c = (t == 0) ? (iv * gv) : (fv * c_st[rg] + iv * gv);
      c_st[rg] = c;
      hn[rg] = ov * ftnh(c);
    }
    if (t < 5) {
#pragma unroll
      for (int rg = 0; rg < 4; ++rg) {
        int rr = r0 + rg;
        sHb[(t & 1) * 2048 + rr * 128 + (hcol ^ ((rr & 7) << 3))] = f2bf(hn[rg]);
      }
      __syncthreads();
    } else {
#pragma unroll
      for (int rg = 0; rg < 4; ++rg) {
        if (nn[rg] < cnt) {
          int off = dswz ? (hcol ^ ((nn[rg] & 7) << 3)) : hcol;
          hdst[((size_t)d * dstride + nn[rg]) * 128 + off] = f2bf(hn[rg]);
        }
      }
    }
  }
}

// Levels 6..0 + head. 64 blocks, one per L3 subtree; both dirs in-block.
// Levels 6,5,4,3 fully local (h in LDS); one arrival-only sync; block 0
// finishes levels 2,1,0 + final head.
__global__ __launch_bounds__(512) void coop_tail3(
    const int* __restrict__ labels, const ushort* __restrict__ gxv,
    const ushort* __restrict__ h7, ushort* __restrict__ h3,
    const ushort* __restrict__ wihrep, const ushort* __restrict__ whhrep,
    const ushort* __restrict__ linrep, const float* __restrict__ linb,
    const float* __restrict__ bihf, const float* __restrict__ bhhf,
    const float* __restrict__ bihb, const float* __restrict__ bhhb,
    float* __restrict__ outp, unsigned* __restrict__ bar) {
  __shared__ __align__(16) ushort sG[32768];
  __shared__ __align__(16) ushort sT[2048];
  __shared__ __align__(16) ushort sHb[4096];
  __shared__ __align__(16) ushort sH6[16384];  // [2][64][128] swz
  __shared__ __align__(16) ushort sH5[4096];   // [2][16][128] swz
  __shared__ __align__(16) ushort sH4[2048];   // [2][8][128] swz
  const int b = blockIdx.x;

  // L6: 64 nodes (4 tiles) per dir; children h7 global rows [256b,256b+256)
  for (int d = 0; d < 2; ++d)
    for (int tt = 0; tt < 4; ++tt) {
      scan_embed2(tt, d, 64, labels + 1365 + 64 * b, gxv,
                  h7 + (size_t)256 * b * 128, 16384, 256, false, sH6, 64, true,
                  wihrep, whhrep, linrep, linb, bihf, bhhf, bihb, bhhb, sG,
                  sHb, sT);
      __syncthreads();
    }
  // L5: 16 nodes; children sH6
  for (int d = 0; d < 2; ++d) {
    scan_embed2(0, d, 16, labels + 341 + 16 * b, gxv, sH6, 64, 64, true, sH5,
                16, true, wihrep, whhrep, linrep, linb, bihf, bhhf, bihb,
                bhhb, sG, sHb, sT);
    __syncthreads();
  }
  // L4: 4 nodes; children sH5
  for (int d = 0; d < 2; ++d) {
    scan_embed2(0, d, 4, labels + 85 + 4 * b, gxv, sH5, 16, 16, true, sH4, 8,
                true, wihrep, whhrep, linrep, linb, bihf, bhhf, bihb, bhhb,
                sG, sHb, sT);
    __syncthreads();
  }
  // L3: 1 node; children sH4; -> h3 global row b
  for (int d = 0; d < 2; ++d) {
    scan_embed2(0, d, 1, labels + 21 + b, gxv, sH4, 8, 4, true,
                h3 + (size_t)b * 128, 64, false, wihrep, whhrep, linrep, linb,
                bihf, bhhf, bihb, bhhb, sG, sHb, sT);
    __syncthreads();
  }

  // arrival (no broadcast): blocks !=0 post and exit
  if (threadIdx.x == 0) {
    __builtin_amdgcn_fence(__ATOMIC_RELEASE, "agent");
    __hip_atomic_fetch_add(&bar[(b & 7) * 32], 1u, __ATOMIC_RELAXED,
                           __HIP_MEMORY_SCOPE_AGENT);
  }
  if (b != 0) return;
  if (threadIdx.x == 0) {
    unsigned sum;
    do {
      __builtin_amdgcn_s_sleep(4);
      sum = 0;
#pragma unroll
      for (int i = 0; i < 8; ++i)
        sum += __hip_atomic_load(&bar[i * 32], __ATOMIC_RELAXED,
                                 __HIP_MEMORY_SCOPE_AGENT);
    } while (sum < 64u);
    __builtin_amdgcn_fence(__ATOMIC_ACQUIRE, "agent");
  }
  __syncthreads();

  // L2: 16 nodes; children h3 global (64 rows)
  for (int d = 0; d < 2; ++d) {
    scan_embed2(0, d, 16, labels + 5, gxv, h3, 64, 64, false, sH5, 16, true,
                wihrep, whhrep, linrep, linb, bihf, bhhf, bihb, bhhb, sG, sHb,
                sT);
    __syncthreads();
  }
  // L1: 4 nodes; children sH5
  for (int d = 0; d < 2; ++d) {
    scan_embed2(0, d, 4, labels + 1, gxv, sH5, 16, 16, true, sH4, 8, true,
                wihrep, whhrep, linrep, linb, bihf, bhhf, bihb, bhhb, sG, sHb,
                sT);
    __syncthreads();
  }
  // L0: 1 node; children sH4; -> sH6 row 0 (swz key 0 = linear)
  for (int d = 0; d < 2; ++d) {
    scan_embed2(0, d, 1, labels + 0, gxv, sH4, 8, 4, true, sH6, 16, true,
                wihrep, whhrep, linrep, linb, bihf, bhhf, bihb, bhhb, sG, sHb,
                sT);
    __syncthreads();
  }
  // final head of node 0 from sH6
  const int tid = threadIdx.x;
  const int w = tid >> 6, l = tid & 63, hlo = l & 15, lg = l >> 4;
  const float lb = linb[w * 16 + hlo];
  f32x4 hac = {lb, lb, lb, lb};
#pragma unroll
  for (int kk = 0; kk < 8; ++kk) {
    bf16x8 lf = *(const bf16x8*)(linrep + w * 4096 + kk * 512 + l * 8);
    bf16x8 af = *(const bf16x8*)(sH6 + ((size_t)(kk >> 2) * 16) * 128 +
                                 (kk & 3) * 32 + lg * 8);
    hac = MF(af, lf, hac);
  }
  if (lg == 0) outp[w * 16 + hlo] = ftnh(hac[0]);
}

extern "C" void kernel_launch(void* const* d_in, const int* in_sizes, int n_in,
                              void* d_out, int out_size, void* d_ws, size_t ws_size,
                              hipStream_t stream) {
  const int* labels = (const int*)d_in[0];
  const float* emb = (const float*)d_in[1];
  const float* w_ih_f = (const float*)d_in[2];
  const float* w_hh_f = (const float*)d_in[3];
  const float* b_ih_f = (const float*)d_in[4];
  const float* b_hh_f = (const float*)d_in[5];
  const float* w_ih_b = (const float*)d_in[6];
  const float* w_hh_b = (const float*)d_in[7];
  const float* b_ih_b = (const float*)d_in[8];
  const float* b_hh_b = (const float*)d_in[9];
  const float* lin_w = (const float*)d_in[10];
  const float* lin_b = (const float*)d_in[11];
  float* out = (float*)d_out;

  unsigned* bar = (unsigned*)d_ws;       // 4096 B
  ushort* W = (ushort*)d_ws;
  ushort* gxv = W + 2048;                // 1,048,576
  ushort* gcv = gxv + 1048576;           // 1,048,576
  ushort* h7 = gcv + 1048576;            // 2*16384*128
  ushort* h3 = h7 + 4194304;             // 2*64*128
  ushort* wall = h3 + 16384;             // 425,984
  ushort* whhrep = wall;
  ushort* wihrep = wall + 131072;
  ushort* linrep = wall + 262144;
  ushort* emb_bf = wall + 294912;

  hipMemsetAsync(bar, 0, 4096, stream);
  repack_all2<<<1664, 256, 0, stream>>>(w_ih_f, w_hh_f, w_ih_b, w_hh_b, emb,
                                        lin_w, wall);
  vocab_all<<<64, 512, 0, stream>>>(emb_bf, wihrep, whhrep, linrep, lin_b,
                                    b_ih_f, b_hh_f, b_ih_b, b_hh_b, gxv, gcv);
  scan7_k<<<dim3(1024, 2), 512, 0, stream>>>(labels, gxv, gcv, whhrep, b_ih_f,
                                             b_hh_f, b_ih_b, b_hh_b, h7);
  coop_tail3<<<64, 512, 0, stream>>>(labels, gxv, h7, h3, wihrep, whhrep,
                                     linrep, lin_b, b_ih_f, b_hh_f, b_ih_b,
                                     b_hh_b, out, bar);
}

// Round 10
// 338.666 us; speedup vs baseline: 1.1872x; 1.1872x over previous
//
#include <hip/hip_runtime.h>
#include <hip/hip_bf16.h>

typedef __attribute__((ext_vector_type(8))) short bf16x8;
typedef __attribute__((ext_vector_type(4))) float f32x4;

__device__ __forceinline__ ushort f2bf(float f) {
  union { float f; unsigned u; } v; v.f = f;
  unsigned u = v.u;
  return (ushort)((u + 0x7FFFu + ((u >> 16) & 1u)) >> 16);
}
__device__ __forceinline__ float bf2f(ushort u) {
  union { unsigned u; float f; } v; v.u = ((unsigned)u) << 16;
  return v.f;
}
__device__ __forceinline__ float fsig(float x) {
  return __builtin_amdgcn_rcpf(1.0f + __expf(-x));
}
__device__ __forceinline__ float ftnh(float x) {
  float e = __expf(2.0f * x);
  return 1.0f - 2.0f * __builtin_amdgcn_rcpf(e + 1.0f);
}
__device__ __forceinline__ f32x4 MF(bf16x8 a, bf16x8 b, f32x4 c) {
  return __builtin_amdgcn_mfma_f32_16x16x32_bf16(a, b, c, 0, 0, 0);
}

// Repack layout (ushort units) in `wall`:
//  [0,131072)        whhrep [dir2][w8][lane64][frag16][8]
//  [131072,262144)   wihrep [dir2][wq4][j8][kk4][lane64][8]
//  [262144,294912)   linrep [w8][kk8][lane64][8]
//  [294912,425984)   emb_bf [1024][128]
__global__ __launch_bounds__(256) void repack_all2(
    const float* __restrict__ wihf, const float* __restrict__ whhf,
    const float* __restrict__ wihb, const float* __restrict__ whhb,
    const float* __restrict__ emb, const float* __restrict__ linw,
    ushort* __restrict__ wall) {
  int i = blockIdx.x * 256 + threadIdx.x;
  if (i < 131072) {
    int e = i & 7, f = (i >> 3) & 15, lane = (i >> 7) & 63, w = (i >> 13) & 7,
        d = (i >> 16) & 1;
    int nt = f >> 2, kk = f & 3;
    int pcol = w * 64 + nt * 16 + (lane & 15);
    int g = (pcol >> 4) & 3, h = (pcol >> 6) * 16 + (pcol & 15);
    int k = kk * 32 + (lane >> 4) * 8 + e;
    const float* src = d ? whhb : whhf;
    wall[i] = f2bf(src[(g * 128 + h) * 128 + k]);
  } else if (i < 262144) {
    int r = i - 131072;
    int e = r & 7, lane = (r >> 3) & 63, kk = (r >> 9) & 3, j = (r >> 11) & 7,
        wq = (r >> 14) & 3, d = (r >> 16) & 1;
    int pcol = wq * 128 + j * 16 + (lane & 15);
    int g = (pcol >> 4) & 3, h = (pcol >> 6) * 16 + (pcol & 15);
    int k = kk * 32 + (lane >> 4) * 8 + e;
    const float* src = d ? wihb : wihf;
    wall[i] = f2bf(src[(g * 128 + h) * 128 + k]);
  } else if (i < 294912) {
    int r = i - 262144;
    int e = r & 7, lane = (r >> 3) & 63, kk = (r >> 9) & 7, w = (r >> 12) & 7;
    int col = w * 16 + (lane & 15);
    int k = kk * 32 + (lane >> 4) * 8 + e;
    wall[i] = f2bf(linw[col * 256 + k]);
  } else if (i < 425984) {
    int r = i - 294912;
    wall[i] = f2bf(emb[r]);
  }
}

// Fused vocab pipeline: x-gates (-> gxv), leaf scan (T=2), leaf head+gates
// (-> gcv). One block per 16 vocab entries. (Unchanged from round 9.)
__global__ __launch_bounds__(512) void vocab_all(
    const ushort* __restrict__ emb_bf, const ushort* __restrict__ wihrep,
    const ushort* __restrict__ whhrep, const ushort* __restrict__ linrep,
    const float* __restrict__ linb, const float* __restrict__ bihf,
    const float* __restrict__ bhhf, const float* __restrict__ bihb,
    const float* __restrict__ bhhb, ushort* __restrict__ gxv,
    ushort* __restrict__ gcv) {
  __shared__ __align__(16) ushort sT[2048];
  __shared__ __align__(16) ushort sGx[16384];
  __shared__ __align__(16) ushort sHf[2][2048];
  __shared__ __align__(16) ushort sH[2048];
  const int tid = threadIdx.x;
  const int w = tid >> 6, l = tid & 63, hlo = l & 15, lg = l >> 4;
  const int r0 = lg * 4, k0 = lg * 8;
  const int hcol = w * 16 + hlo;
  const int v0 = blockIdx.x * 16;

  {
    int row = tid >> 5, col0 = (tid & 31) * 4;
    *(ushort4*)(sT + row * 128 + (col0 ^ ((row & 7) << 3))) =
        *(const ushort4*)(emb_bf + (size_t)(v0 + row) * 128 + col0);
  }
  __syncthreads();
  const int dd = w >> 2, wq = w & 3;
  {
    const ushort* wp = wihrep + (size_t)(dd * 4 + wq) * 16384 + l * 8;
    bf16x8 wfv[32];
#pragma unroll
    for (int j = 0; j < 8; ++j)
#pragma unroll
      for (int kk = 0; kk < 4; ++kk)
        wfv[j * 4 + kk] = *(const bf16x8*)(wp + j * 2048 + kk * 512);
    bf16x8 a[4];
#pragma unroll
    for (int kk = 0; kk < 4; ++kk)
      a[kk] = *(const bf16x8*)(sT + hlo * 128 + ((kk * 32 + k0) ^ ((hlo & 7) << 3)));
    f32x4 acc[8];
#pragma unroll
    for (int j = 0; j < 8; ++j) { f32x4 z = {0.f, 0.f, 0.f, 0.f}; acc[j] = z; }
#pragma unroll
    for (int kk = 0; kk < 4; ++kk)
#pragma unroll
      for (int j = 0; j < 8; ++j) acc[j] = MF(a[kk], wfv[j * 4 + kk], acc[j]);
#pragma unroll
    for (int p = 0; p < 2; ++p)
#pragma unroll
      for (int rg = 0; rg < 4; ++rg) {
        int hid = (wq * 2 + p) * 16 + hlo;
        ushort4 q = {f2bf(acc[p * 4 + 0][rg]), f2bf(acc[p * 4 + 1][rg]),
                     f2bf(acc[p * 4 + 2][rg]), f2bf(acc[p * 4 + 3][rg])};
        *(ushort4*)(gxv + (size_t)(v0 + r0 + rg) * 1024 + dd * 512 + hid * 4) = q;
        *(ushort4*)(sGx + (r0 + rg) * 1024 + dd * 512 + hid * 4) = q;
      }
  }
  __syncthreads();

  for (int d = 0; d < 2; ++d) {
    bf16x8 whh[16];
    {
      const ushort* p = whhrep + d * 65536 + w * 8192 + l * 128;
#pragma unroll
      for (int f = 0; f < 16; ++f) whh[f] = *(const bf16x8*)(p + f * 8);
    }
    const float* bih = d ? bihb : bihf;
    const float* bhh = d ? bhhb : bhhf;
    float bs[4];
#pragma unroll
    for (int nt = 0; nt < 4; ++nt)
      bs[nt] = bih[nt * 128 + hcol] + bhh[nt * 128 + hcol];
    ushort4 xg[4];
#pragma unroll
    for (int rg = 0; rg < 4; ++rg)
      xg[rg] = *(const ushort4*)(sGx + (r0 + rg) * 1024 + d * 512 + hcol * 4);
    float c_st[4], hn[4];
#pragma unroll
    for (int rg = 0; rg < 4; ++rg) {
      float g0 = bf2f(((const ushort*)&xg[rg])[0]) + bs[0];
      float g2 = bf2f(((const ushort*)&xg[rg])[2]) + bs[2];
      float g3 = bf2f(((const ushort*)&xg[rg])[3]) + bs[3];
      float c = fsig(g0) * ftnh(g2);
      c_st[rg] = c;
      hn[rg] = fsig(g3) * ftnh(c);
    }
#pragma unroll
    for (int rg = 0; rg < 4; ++rg) {
      int rr = r0 + rg;
      sH[rr * 128 + (hcol ^ ((rr & 7) << 3))] = f2bf(hn[rg]);
    }
    __syncthreads();
    f32x4 a4[4];
#pragma unroll
    for (int rg = 0; rg < 4; ++rg)
#pragma unroll
      for (int nt = 0; nt < 4; ++nt)
        a4[nt][rg] = bf2f(((const ushort*)&xg[rg])[nt]) + bs[nt];
    bf16x8 ah[4];
#pragma unroll
    for (int kk = 0; kk < 4; ++kk)
      ah[kk] = *(const bf16x8*)(sH + hlo * 128 + ((kk * 32 + k0) ^ ((hlo & 7) << 3)));
#pragma unroll
    for (int kk = 0; kk < 4; ++kk)
#pragma unroll
      for (int nt = 0; nt < 4; ++nt) a4[nt] = MF(ah[kk], whh[nt * 4 + kk], a4[nt]);
#pragma unroll
    for (int rg = 0; rg < 4; ++rg) {
      float iv = fsig(a4[0][rg]);
      float fv = fsig(a4[1][rg]);
      float gv = ftnh(a4[2][rg]);
      float ov = fsig(a4[3][rg]);
      float c = fv * c_st[rg] + iv * gv;
      int rr = r0 + rg;
      sHf[d][rr * 128 + (hcol ^ ((rr & 7) << 3))] = f2bf(ov * ftnh(c));
    }
    __syncthreads();
  }

  {
    const float lb = linb[hcol];
    f32x4 hac = {lb, lb, lb, lb};
#pragma unroll
    for (int kk = 0; kk < 8; ++kk) {
      bf16x8 lf = *(const bf16x8*)(linrep + w * 4096 + kk * 512 + l * 8);
      bf16x8 af = *(const bf16x8*)(&sHf[kk >> 2][0] + hlo * 128 +
                                   (((kk & 3) * 32 + k0) ^ ((hlo & 7) << 3)));
      hac = MF(af, lf, hac);
    }
#pragma unroll
    for (int rg = 0; rg < 4; ++rg) {
      int rr = r0 + rg;
      sT[rr * 128 + (hcol ^ ((rr & 7) << 3))] = f2bf(ftnh(hac[rg]));
    }
    __syncthreads();
    const ushort* wp = wihrep + (size_t)(dd * 4 + wq) * 16384 + l * 8;
    bf16x8 wfv[32];
#pragma unroll
    for (int j = 0; j < 8; ++j)
#pragma unroll
      for (int kk = 0; kk < 4; ++kk)
        wfv[j * 4 + kk] = *(const bf16x8*)(wp + j * 2048 + kk * 512);
    bf16x8 a[4];
#pragma unroll
    for (int kk = 0; kk < 4; ++kk)
      a[kk] = *(const bf16x8*)(sT + hlo * 128 + ((kk * 32 + k0) ^ ((hlo & 7) << 3)));
    f32x4 acc[8];
#pragma unroll
    for (int j = 0; j < 8; ++j) { f32x4 z = {0.f, 0.f, 0.f, 0.f}; acc[j] = z; }
#pragma unroll
    for (int kk = 0; kk < 4; ++kk)
#pragma unroll
      for (int j = 0; j < 8; ++j) acc[j] = MF(a[kk], wfv[j * 4 + kk], acc[j]);
#pragma unroll
    for (int p = 0; p < 2; ++p)
#pragma unroll
      for (int rg = 0; rg < 4; ++rg) {
        int hid = (wq * 2 + p) * 16 + hlo;
        ushort4 q = {f2bf(acc[p * 4 + 0][rg]), f2bf(acc[p * 4 + 1][rg]),
                     f2bf(acc[p * 4 + 2][rg]), f2bf(acc[p * 4 + 3][rg])};
        *(ushort4*)(gcv + (size_t)(v0 + r0 + rg) * 1024 + dd * 512 + hid * 4) = q;
      }
  }
}

// Generic level kernel: scan both dirs for MT*16 nodes (exact fit), then
// head + own-gates -> gdst. Child gates: gsrc rows (CLAB ? label : 4n+ci).
// No global h, no barriers. count must be divisible by MT*16.
template <int MT, bool CLAB>
__global__ __launch_bounds__(512) void scan_lvl(
    const int* __restrict__ xlab, const int* __restrict__ clab,
    const ushort* __restrict__ gxv, const ushort* __restrict__ gsrc,
    const ushort* __restrict__ wihrep, const ushort* __restrict__ whhrep,
    const ushort* __restrict__ linrep, const float* __restrict__ linb,
    const float* __restrict__ bihf, const float* __restrict__ bhhf,
    const float* __restrict__ bihb, const float* __restrict__ bhhb,
    ushort* __restrict__ gdst, int count) {
  __shared__ __align__(16) ushort sH[2][MT * 2048];
  __shared__ __align__(16) ushort sHF[2][MT * 2048];
  __shared__ __align__(16) ushort sT[2048];
  __shared__ int sLab[MT * 64];

  const int tid = threadIdx.x;
  const int w = tid >> 6, l = tid & 63, hlo = l & 15, lg = l >> 4;
  const int r0 = lg * 4, k0 = lg * 8;
  const int hcol = w * 16 + hlo;
  const int axswz = (hlo & 7) << 3;
  const int nb0 = blockIdx.x * (MT * 16);

  if (CLAB) {
    for (int i = tid; i < MT * 64; i += 512) sLab[i] = clab[4 * nb0 + i];
    __syncthreads();
  }

  for (int d = 0; d < 2; ++d) {
    bf16x8 whh[16];
    {
      const ushort* p = whhrep + d * 65536 + w * 8192 + l * 128;
#pragma unroll
      for (int f = 0; f < 16; ++f) whh[f] = *(const bf16x8*)(p + f * 8);
    }
    const float* bih = d ? bihb : bihf;
    const float* bhh = d ? bhhb : bhhf;
    float bs[4];
#pragma unroll
    for (int nt = 0; nt < 4; ++nt)
      bs[nt] = bih[nt * 128 + hcol] + bhh[nt * 128 + hcol];

    ushort4 xg[MT][4], cur[MT][4];
#pragma unroll
    for (int mt = 0; mt < MT; ++mt)
#pragma unroll
      for (int rg = 0; rg < 4; ++rg) {
        int n = nb0 + mt * 16 + r0 + rg;
        xg[mt][rg] = *(const ushort4*)(gxv + (size_t)xlab[n] * 1024 + d * 512 +
                                       hcol * 4);
        cur[mt][rg] = xg[mt][rg];
      }

    float c_st[MT][4];
#pragma unroll
    for (int t = 0; t < 6; ++t) {
      ushort4 nxt[MT][4];
      if (t < 4) {
        const int ci = d ? (3 - t) : t;  // child index for step t+1
#pragma unroll
        for (int mt = 0; mt < MT; ++mt)
#pragma unroll
          for (int rg = 0; rg < 4; ++rg) {
            int ln = mt * 16 + r0 + rg;
            int row = CLAB ? sLab[ln * 4 + ci] : (4 * (nb0 + ln) + ci);
            nxt[mt][rg] = *(const ushort4*)(gsrc + (size_t)row * 1024 +
                                            d * 512 + hcol * 4);
          }
      }
#pragma unroll
      for (int mt = 0; mt < MT; ++mt) {
        f32x4 a4[4];
#pragma unroll
        for (int rg = 0; rg < 4; ++rg) {
          ushort4 u = (t == 5) ? xg[mt][rg] : cur[mt][rg];
#pragma unroll
          for (int nt = 0; nt < 4; ++nt)
            a4[nt][rg] = bf2f(((const ushort*)&u)[nt]) + bs[nt];
        }
        if (t > 0) {
          bf16x8 ah[4];
#pragma unroll
          for (int kk = 0; kk < 4; ++kk)
            ah[kk] = *(const bf16x8*)(&sH[(t + 1) & 1][mt * 2048] + hlo * 128 +
                                      ((kk * 32 + k0) ^ axswz));
#pragma unroll
          for (int kk = 0; kk < 4; ++kk)
#pragma unroll
            for (int nt = 0; nt < 4; ++nt)
              a4[nt] = MF(ah[kk], whh[nt * 4 + kk], a4[nt]);
        }
        float hn[4];
#pragma unroll
        for (int rg = 0; rg < 4; ++rg) {
          float iv = fsig(a4[0][rg]);
          float fv = fsig(a4[1][rg]);
          float gv = ftnh(a4[2][rg]);
          float ov = fsig(a4[3][rg]);
          float c = (t == 0) ? (iv * gv) : (fv * c_st[mt][rg] + iv * gv);
          c_st[mt][rg] = c;
          hn[rg] = ov * ftnh(c);
        }
        ushort* dstp = (t < 5) ? &sH[t & 1][mt * 2048] : &sHF[d][mt * 2048];
#pragma unroll
        for (int rg = 0; rg < 4; ++rg) {
          int rr = r0 + rg;
          dstp[rr * 128 + (hcol ^ ((rr & 7) << 3))] = f2bf(hn[rg]);
        }
      }
      if (t < 4) {
#pragma unroll
        for (int mt = 0; mt < MT; ++mt)
#pragma unroll
          for (int rg = 0; rg < 4; ++rg) cur[mt][rg] = nxt[mt][rg];
      }
      __syncthreads();
    }
  }

  // ---- head + own gates ----
  const int dd = w >> 2, wq = w & 3;
  bf16x8 lf[8], wf[32];
#pragma unroll
  for (int kk = 0; kk < 8; ++kk)
    lf[kk] = *(const bf16x8*)(linrep + w * 4096 + kk * 512 + l * 8);
  {
    const ushort* wp = wihrep + (size_t)(dd * 4 + wq) * 16384 + l * 8;
#pragma unroll
    for (int j = 0; j < 8; ++j)
#pragma unroll
      for (int kk = 0; kk < 4; ++kk)
        wf[j * 4 + kk] = *(const bf16x8*)(wp + j * 2048 + kk * 512);
  }
  const float lb = linb[hcol];
#pragma unroll
  for (int mt = 0; mt < MT; ++mt) {
    f32x4 hac = {lb, lb, lb, lb};
#pragma unroll
    for (int kk = 0; kk < 8; ++kk) {
      bf16x8 af = *(const bf16x8*)(&sHF[kk >> 2][mt * 2048] + hlo * 128 +
                                   (((kk & 3) * 32 + k0) ^ axswz));
      hac = MF(af, lf[kk], hac);
    }
    __syncthreads();
#pragma unroll
    for (int rg = 0; rg < 4; ++rg) {
      int rr = r0 + rg;
      sT[rr * 128 + (hcol ^ ((rr & 7) << 3))] = f2bf(ftnh(hac[rg]));
    }
    __syncthreads();
    bf16x8 a[4];
#pragma unroll
    for (int kk = 0; kk < 4; ++kk)
      a[kk] = *(const bf16x8*)(sT + hlo * 128 + ((kk * 32 + k0) ^ axswz));
    f32x4 acc[8];
#pragma unroll
    for (int j = 0; j < 8; ++j) { f32x4 z = {0.f, 0.f, 0.f, 0.f}; acc[j] = z; }
#pragma unroll
    for (int kk = 0; kk < 4; ++kk)
#pragma unroll
      for (int j = 0; j < 8; ++j) acc[j] = MF(a[kk], wf[j * 4 + kk], acc[j]);
#pragma unroll
    for (int p = 0; p < 2; ++p)
#pragma unroll
      for (int rg = 0; rg < 4; ++rg) {
        int n = nb0 + mt * 16 + r0 + rg;
        int hid = (wq * 2 + p) * 16 + hlo;
        ushort4 q = {f2bf(acc[p * 4 + 0][rg]), f2bf(acc[p * 4 + 1][rg]),
                     f2bf(acc[p * 4 + 2][rg]), f2bf(acc[p * 4 + 3][rg])};
        *(ushort4*)(gdst + (size_t)n * 1024 + dd * 512 + hid * 4) = q;
      }
  }
}

// Levels 2,1,0 + final head in ONE block; gates routed through LDS.
__global__ __launch_bounds__(512) void tail_lvls(
    const int* __restrict__ labels, const ushort* __restrict__ gxv,
    const ushort* __restrict__ gc3, const ushort* __restrict__ wihrep,
    const ushort* __restrict__ whhrep, const ushort* __restrict__ linrep,
    const float* __restrict__ linb, const float* __restrict__ bihf,
    const float* __restrict__ bhhf, const float* __restrict__ bihb,
    const float* __restrict__ bhhb, float* __restrict__ outp) {
  __shared__ __align__(16) ushort sH[2][2048];
  __shared__ __align__(16) ushort sHF[2][2048];
  __shared__ __align__(16) ushort sT[2048];
  __shared__ __align__(16) ushort sGc[16384];  // 16 rows x 1024

  const int tid = threadIdx.x;
  const int w = tid >> 6, l = tid & 63, hlo = l & 15, lg = l >> 4;
  const int r0 = lg * 4, k0 = lg * 8;
  const int hcol = w * 16 + hlo;
  const int axswz = (hlo & 7) << 3;
  const int dd = w >> 2, wq = w & 3;

  bf16x8 lf[8], wf[32];
#pragma unroll
  for (int kk = 0; kk < 8; ++kk)
    lf[kk] = *(const bf16x8*)(linrep + w * 4096 + kk * 512 + l * 8);
  {
    const ushort* wp = wihrep + (size_t)(dd * 4 + wq) * 16384 + l * 8;
#pragma unroll
    for (int j = 0; j < 8; ++j)
#pragma unroll
      for (int kk = 0; kk < 4; ++kk)
        wf[j * 4 + kk] = *(const bf16x8*)(wp + j * 2048 + kk * 512);
  }
  const float lb = linb[hcol];
  const int cnts[3] = {16, 4, 1};
  const int xoffs[3] = {5, 1, 0};

  for (int p = 0; p < 3; ++p) {
    const int cnt = cnts[p];
    const int* xlab = labels + xoffs[p];
    const ushort* gsrc = (p == 0) ? gc3 : (const ushort*)sGc;
    int nnr[4];
#pragma unroll
    for (int rg = 0; rg < 4; ++rg) {
      int n = r0 + rg;
      nnr[rg] = (n < cnt) ? n : (cnt - 1);
    }

    for (int d = 0; d < 2; ++d) {
      bf16x8 whh[16];
      {
        const ushort* pw = whhrep + d * 65536 + w * 8192 + l * 128;
#pragma unroll
        for (int f = 0; f < 16; ++f) whh[f] = *(const bf16x8*)(pw + f * 8);
      }
      const float* bih = d ? bihb : bihf;
      const float* bhh = d ? bhhb : bhhf;
      float bs[4];
#pragma unroll
      for (int nt = 0; nt < 4; ++nt)
        bs[nt] = bih[nt * 128 + hcol] + bhh[nt * 128 + hcol];

      ushort4 xg[4], cur[4];
#pragma unroll
      for (int rg = 0; rg < 4; ++rg) {
        xg[rg] = *(const ushort4*)(gxv + (size_t)xlab[nnr[rg]] * 1024 +
                                   d * 512 + hcol * 4);
        cur[rg] = xg[rg];
      }
      float c_st[4];
#pragma unroll
      for (int t = 0; t < 6; ++t) {
        ushort4 nxt[4];
        if (t < 4) {
          const int ci = d ? (3 - t) : t;
#pragma unroll
          for (int rg = 0; rg < 4; ++rg) {
            int row = 4 * nnr[rg] + ci;
            nxt[rg] = *(const ushort4*)(gsrc + (size_t)row * 1024 + d * 512 +
                                        hcol * 4);
          }
        }
        f32x4 a4[4];
#pragma unroll
        for (int rg = 0; rg < 4; ++rg) {
          ushort4 u = (t == 5) ? xg[rg] : cur[rg];
#pragma unroll
          for (int nt = 0; nt < 4; ++nt)
            a4[nt][rg] = bf2f(((const ushort*)&u)[nt]) + bs[nt];
        }
        if (t > 0) {
          bf16x8 ah[4];
#pragma unroll
          for (int kk = 0; kk < 4; ++kk)
            ah[kk] = *(const bf16x8*)(&sH[(t + 1) & 1][0] + hlo * 128 +
                                      ((kk * 32 + k0) ^ axswz));
#pragma unroll
          for (int kk = 0; kk < 4; ++kk)
#pragma unroll
            for (int nt = 0; nt < 4; ++nt)
              a4[nt] = MF(ah[kk], whh[nt * 4 + kk], a4[nt]);
        }
        float hn[4];
#pragma unroll
        for (int rg = 0; rg < 4; ++rg) {
          float iv = fsig(a4[0][rg]);
          float fv = fsig(a4[1][rg]);
          float gv = ftnh(a4[2][rg]);
          float ov = fsig(a4[3][rg]);
          float c = (t == 0) ? (iv * gv) : (fv * c_st[rg] + iv * gv);
          c_st[rg] = c;
          hn[rg] = ov * ftnh(c);
        }
        ushort* dstp = (t < 5) ? &sH[t & 1][0] : &sHF[d][0];
#pragma unroll
        for (int rg = 0; rg < 4; ++rg) {
          int rr = r0 + rg;
          dstp[rr * 128 + (hcol ^ ((rr & 7) << 3))] = f2bf(hn[rg]);
        }
        if (t < 4) {
#pragma unroll
          for (int rg = 0; rg < 4; ++rg) cur[rg] = nxt[rg];
        }
        __syncthreads();
      }
    }

    // head of this level's tile
    f32x4 hac = {lb, lb, lb, lb};
#pragma unroll
    for (int kk = 0; kk < 8; ++kk) {
      bf16x8 af = *(const bf16x8*)(&sHF[kk >> 2][0] + hlo * 128 +
                                   (((kk & 3) * 32 + k0) ^ axswz));
      hac = MF(af, lf[kk], hac);
    }
    if (p == 2) {
      if (lg == 0) outp[hcol] = ftnh(hac[0]);
      return;
    }
    __syncthreads();
#pragma unroll
    for (int rg = 0; rg < 4; ++rg) {
      int rr = r0 + rg;
      sT[rr * 128 + (hcol ^ ((rr & 7) << 3))] = f2bf(ftnh(hac[rg]));
    }
    __syncthreads();
    bf16x8 a[4];
#pragma unroll
    for (int kk = 0; kk < 4; ++kk)
      a[kk] = *(const bf16x8*)(sT + hlo * 128 + ((kk * 32 + k0) ^ axswz));
    f32x4 acc[8];
#pragma unroll
    for (int j = 0; j < 8; ++j) { f32x4 z = {0.f, 0.f, 0.f, 0.f}; acc[j] = z; }
#pragma unroll
    for (int kk = 0; kk < 4; ++kk)
#pragma unroll
      for (int j = 0; j < 8; ++j) acc[j] = MF(a[kk], wf[j * 4 + kk], acc[j]);
#pragma unroll
    for (int pp = 0; pp < 2; ++pp)
#pragma unroll
      for (int rg = 0; rg < 4; ++rg) {
        int n = r0 + rg;
        if (n < cnt) {
          int hid = (wq * 2 + pp) * 16 + hlo;
          ushort4 q = {f2bf(acc[pp * 4 + 0][rg]), f2bf(acc[pp * 4 + 1][rg]),
                       f2bf(acc[pp * 4 + 2][rg]), f2bf(acc[pp * 4 + 3][rg])};
          *(ushort4*)(sGc + (size_t)n * 1024 + dd * 512 + hid * 4) = q;
        }
      }
    __syncthreads();
  }
}

extern "C" void kernel_launch(void* const* d_in, const int* in_sizes, int n_in,
                              void* d_out, int out_size, void* d_ws, size_t ws_size,
                              hipStream_t stream) {
  const int* labels = (const int*)d_in[0];
  const float* emb = (const float*)d_in[1];
  const float* w_ih_f = (const float*)d_in[2];
  const float* w_hh_f = (const float*)d_in[3];
  const float* b_ih_f = (const float*)d_in[4];
  const float* b_hh_f = (const float*)d_in[5];
  const float* w_ih_b = (const float*)d_in[6];
  const float* w_hh_b = (const float*)d_in[7];
  const float* b_ih_b = (const float*)d_in[8];
  const float* b_hh_b = (const float*)d_in[9];
  const float* lin_w = (const float*)d_in[10];
  const float* lin_b = (const float*)d_in[11];
  float* out = (float*)d_out;

  ushort* W = (ushort*)d_ws;
  ushort* gxv = W;                     // 1,048,576 ushorts
  ushort* gcA = gxv + 1048576;         // 16,777,216 (L7 / L5 / L3 gates)
  ushort* gcB = gcA + 16777216;        // 4,194,304  (gcv alias / L6 / L4 gates)
  ushort* gcv = gcB;
  ushort* wall = gcB + 4194304;        // 425,984
  ushort* whhrep = wall;
  ushort* wihrep = wall + 131072;
  ushort* linrep = wall + 262144;
  ushort* emb_bf = wall + 294912;

  repack_all2<<<1664, 256, 0, stream>>>(w_ih_f, w_hh_f, w_ih_b, w_hh_b, emb,
                                        lin_w, wall);
  vocab_all<<<64, 512, 0, stream>>>(emb_bf, wihrep, whhrep, linrep, lin_b,
                                    b_ih_f, b_hh_f, b_ih_b, b_hh_b, gxv, gcv);
  // L7: 16384 nodes, children = leaves via labels -> gcA
  scan_lvl<4, true><<<256, 512, 0, stream>>>(
      labels + 5461, labels + 21845, gxv, gcv, wihrep, whhrep, linrep, lin_b,
      b_ih_f, b_hh_f, b_ih_b, b_hh_b, gcA, 16384);
  // L6: 4096 -> gcB (overwrites gcv, safe: gcv consumed by L7)
  scan_lvl<4, false><<<64, 512, 0, stream>>>(
      labels + 1365, nullptr, gxv, gcA, wihrep, whhrep, linrep, lin_b, b_ih_f,
      b_hh_f, b_ih_b, b_hh_b, gcB, 4096);
  // L5: 1024 -> gcA rows 0..1023 (gcA free after L6)
  scan_lvl<1, false><<<64, 512, 0, stream>>>(
      labels + 341, nullptr, gxv, gcB, wihrep, whhrep, linrep, lin_b, b_ih_f,
      b_hh_f, b_ih_b, b_hh_b, gcA, 1024);
  // L4: 256 -> gcB rows 0..255
  scan_lvl<1, false><<<16, 512, 0, stream>>>(
      labels + 85, nullptr, gxv, gcA, wihrep, whhrep, linrep, lin_b, b_ih_f,
      b_hh_f, b_ih_b, b_hh_b, gcB, 256);
  // L3: 64 -> gcA rows 0..63
  scan_lvl<1, false><<<4, 512, 0, stream>>>(
      labels + 21, nullptr, gxv, gcB, wihrep, whhrep, linrep, lin_b, b_ih_f,
      b_hh_f, b_ih_b, b_hh_b, gcA, 64);
  // L2+L1+L0+head, one block
  tail_lvls<<<1, 512, 0, stream>>>(labels, gxv, gcA, wihrep, whhrep, linrep,
                                   lin_b, b_ih_f, b_hh_f, b_ih_b, b_hh_b, out);
}